// Round 1
// baseline (3809.219 us; speedup 1.0000x reference)
//
#include <hip/hip_runtime.h>

typedef _Float16 f16x8 __attribute__((ext_vector_type(8)));
typedef _Float16 f16x4 __attribute__((ext_vector_type(4)));
typedef float f32x4 __attribute__((ext_vector_type(4)));

#define NB 4096  // batch

__device__ __forceinline__ void gload16(const void* g, void* l) {
    __builtin_amdgcn_global_load_lds(
        (const __attribute__((address_space(1))) unsigned int*)g,
        (__attribute__((address_space(3))) unsigned int*)l, 16, 0, 0);
}

// ---------------- transpose + fp16-split of initial x: [4096 f][4096 b] -> Xt[b][f] h/l
__global__ __launch_bounds__(256) void tsplit_kernel(const float* __restrict__ X,
                                                     _Float16* __restrict__ Oh,
                                                     _Float16* __restrict__ Ol) {
    __shared__ float t[64][65];
    const int f0 = blockIdx.x * 64, b0 = blockIdx.y * 64;
    const int tid = threadIdx.x;
    const int jj = tid & 63, i0 = tid >> 6;
#pragma unroll
    for (int p = 0; p < 16; ++p) {
        int i = p * 4 + i0;
        t[i][jj] = X[(size_t)(f0 + i) * NB + b0 + jj];
    }
    __syncthreads();
#pragma unroll
    for (int p = 0; p < 16; ++p) {
        int b = p * 4 + i0;
        float v = t[jj][b];
        size_t idx = (size_t)(b0 + b) * 4096 + f0 + jj;
        _Float16 h = (_Float16)v;
        Oh[idx] = h;
        Ol[idx] = (_Float16)((v - (float)h) * 2048.0f);
    }
}

// ---------------- fp16-split of a weight matrix (elementwise)
__global__ __launch_bounds__(256) void splitw_kernel(const float* __restrict__ W,
                                                     _Float16* __restrict__ Wh,
                                                     _Float16* __restrict__ Wl, long n4) {
    long i = (long)blockIdx.x * 256 + threadIdx.x;
    const long stride = (long)gridDim.x * 256;
    for (; i < n4; i += stride) {
        float4 w = ((const float4*)W)[i];
        float vs[4] = {w.x, w.y, w.z, w.w};
        f16x4 h, l;
#pragma unroll
        for (int j = 0; j < 4; ++j) {
            _Float16 hh = (_Float16)vs[j];
            h[j] = hh;
            l[j] = (_Float16)((vs[j] - (float)hh) * 2048.0f);
        }
        ((f16x4*)Wh)[i] = h;
        ((f16x4*)Wl)[i] = l;
    }
}

// ---------------- GEMM: C[n_batch][M] = sum_k Xt[n,k] * W[m,k], fp16x2-split 3-MFMA
// A = Xt h/l [NB][K], B = W h/l [M][K]; optional fused relu.
__global__ __launch_bounds__(256, 2) void gemm3_kernel(
    const _Float16* __restrict__ Ah, const _Float16* __restrict__ Al,
    const _Float16* __restrict__ Bh, const _Float16* __restrict__ Bl,
    float* __restrict__ C, int K, int M, int do_relu) {
    __shared__ __align__(16) _Float16 sAh[128 * 32];
    __shared__ __align__(16) _Float16 sAl[128 * 32];
    __shared__ __align__(16) _Float16 sBh[128 * 32];
    __shared__ __align__(16) _Float16 sBl[128 * 32];

    const int tid = threadIdx.x;
    const int row0 = blockIdx.y * 128;  // batch rows
    const int col0 = blockIdx.x * 128;  // feature cols
    const int wid = tid >> 6, lane = tid & 63;
    const int wm = wid >> 1, wn = wid & 1;
    const int lr = lane & 15, lk = (lane >> 4) * 8;

    f32x4 acc[4][4] = {};
    f32x4 accx[4][4] = {};

    const int o0 = tid * 16;        // byte offset into 8KB tile, call 0
    const int o1 = o0 + 4096;       // call 1
    const int r0 = o0 >> 6, c0 = o0 & 63;
    const int r1 = o1 >> 6, c1 = o1 & 63;
    const size_t sk = (size_t)K * 2;  // bytes per row

    const char* gAh0 = (const char*)Ah + (size_t)(row0 + r0) * sk + c0;
    const char* gAh1 = (const char*)Ah + (size_t)(row0 + r1) * sk + c1;
    const char* gAl0 = (const char*)Al + (size_t)(row0 + r0) * sk + c0;
    const char* gAl1 = (const char*)Al + (size_t)(row0 + r1) * sk + c1;
    const char* gBh0 = (const char*)Bh + (size_t)(col0 + r0) * sk + c0;
    const char* gBh1 = (const char*)Bh + (size_t)(col0 + r1) * sk + c1;
    const char* gBl0 = (const char*)Bl + (size_t)(col0 + r0) * sk + c0;
    const char* gBl1 = (const char*)Bl + (size_t)(col0 + r1) * sk + c1;

    for (int k0 = 0; k0 < K; k0 += 32) {
        __syncthreads();
        gload16(gAh0, (char*)sAh + o0);
        gload16(gAh1, (char*)sAh + o1);
        gload16(gAl0, (char*)sAl + o0);
        gload16(gAl1, (char*)sAl + o1);
        gload16(gBh0, (char*)sBh + o0);
        gload16(gBh1, (char*)sBh + o1);
        gload16(gBl0, (char*)sBl + o0);
        gload16(gBl1, (char*)sBl + o1);
        gAh0 += 64; gAh1 += 64; gAl0 += 64; gAl1 += 64;
        gBh0 += 64; gBh1 += 64; gBl0 += 64; gBl1 += 64;
        __syncthreads();

        f16x8 bh[4], bl[4];
#pragma unroll
        for (int ni = 0; ni < 4; ++ni) {
            int rb = wn * 64 + ni * 16 + lr;
            bh[ni] = *(const f16x8*)&sBh[rb * 32 + lk];
            bl[ni] = *(const f16x8*)&sBl[rb * 32 + lk];
        }
#pragma unroll
        for (int mi = 0; mi < 4; ++mi) {
            int ra = wm * 64 + mi * 16 + lr;
            f16x8 ah = *(const f16x8*)&sAh[ra * 32 + lk];
            f16x8 al = *(const f16x8*)&sAl[ra * 32 + lk];
#pragma unroll
            for (int ni = 0; ni < 4; ++ni) {
                acc[mi][ni] = __builtin_amdgcn_mfma_f32_16x16x32_f16(ah, bh[ni], acc[mi][ni], 0, 0, 0);
                accx[mi][ni] = __builtin_amdgcn_mfma_f32_16x16x32_f16(ah, bl[ni], accx[mi][ni], 0, 0, 0);
                accx[mi][ni] = __builtin_amdgcn_mfma_f32_16x16x32_f16(al, bh[ni], accx[mi][ni], 0, 0, 0);
            }
        }
    }
    // epilogue: combine split accumulators, optional relu, store fp32
#pragma unroll
    for (int mi = 0; mi < 4; ++mi)
#pragma unroll
        for (int ni = 0; ni < 4; ++ni) {
            int colx = col0 + wn * 64 + ni * 16 + lr;
            int rowb = row0 + wm * 64 + mi * 16 + (lane >> 4) * 4;
#pragma unroll
            for (int r = 0; r < 4; ++r) {
                float v = acc[mi][ni][r] + accx[mi][ni][r] * (1.0f / 2048.0f);
                if (do_relu) v = fmaxf(v, 0.0f);
                C[(size_t)(rowb + r) * M + colx] = v;
            }
        }
}

// ---------------- kWTA: exact k-th largest of (x - thr[col]) per row via 4x8-bit radix
// select, then mask.  !SOFTMAX: write fp16 h/l split of masked x (next layer's input).
// SOFTMAX: softmax the masked row and scatter feature-major to outT[feat][batch].
template <int CNT, bool SOFTMAX>
__global__ __launch_bounds__(256) void kwta_kernel(const float* __restrict__ Cin,
                                                   const float* __restrict__ thr,
                                                   _Float16* __restrict__ Oh,
                                                   _Float16* __restrict__ Ol,
                                                   float* __restrict__ outT, int M, int k) {
    const int row = blockIdx.x, tid = threadIdx.x;
    const float* rp = Cin + (size_t)row * M;
    unsigned uv[CNT];
    float xv[CNT];
#pragma unroll
    for (int i = 0; i < CNT; ++i) {
        int col = i * 256 + tid;
        float x = rp[col];
        float a = x - thr[col];
        unsigned b = __float_as_uint(a);
        uv[i] = (b & 0x80000000u) ? ~b : (b | 0x80000000u);  // order-preserving map
        xv[i] = x;
    }
    __shared__ int hist[256];
    __shared__ unsigned sel_s;
    __shared__ int kk_s;
    unsigned prefix = 0;
    int kk = k;
#pragma unroll
    for (int pass = 0; pass < 4; ++pass) {
        const int shift = 24 - pass * 8;
        hist[tid] = 0;
        __syncthreads();
#pragma unroll
        for (int i = 0; i < CNT; ++i) {
            bool ok = (pass == 0) || ((uv[i] >> (shift + 8)) == prefix);
            if (ok) atomicAdd(&hist[(uv[i] >> shift) & 255], 1);
        }
        __syncthreads();
        // suffix sum: hist[t] = count of candidates with chunk >= t
        for (int off = 1; off < 256; off <<= 1) {
            int v = hist[tid] + ((tid + off < 256) ? hist[tid + off] : 0);
            __syncthreads();
            hist[tid] = v;
            __syncthreads();
        }
        if (hist[tid] >= kk && (tid == 255 || hist[tid + 1] < kk)) {
            sel_s = (unsigned)tid;
            kk_s = kk - ((tid == 255) ? 0 : hist[tid + 1]);
        }
        __syncthreads();
        prefix = (prefix << 8) | sel_s;
        kk = kk_s;
        __syncthreads();
    }
    const unsigned kth = prefix;  // u-map of exact k-th largest act
    if (!SOFTMAX) {
#pragma unroll
        for (int i = 0; i < CNT; ++i) {
            int col = i * 256 + tid;
            float v = (uv[i] >= kth) ? xv[i] : 0.0f;
            size_t idx = (size_t)row * M + col;
            _Float16 h = (_Float16)v;
            Oh[idx] = h;
            Ol[idx] = (_Float16)((v - (float)h) * 2048.0f);
        }
    } else {
        float vals[CNT];
        float m = -3.4e38f;
#pragma unroll
        for (int i = 0; i < CNT; ++i) {
            float v = (uv[i] >= kth) ? xv[i] : 0.0f;
            vals[i] = v;
            m = fmaxf(m, v);
        }
        for (int off = 32; off; off >>= 1) m = fmaxf(m, __shfl_xor(m, off));
        __shared__ float redm[4];
        if ((tid & 63) == 0) redm[tid >> 6] = m;
        __syncthreads();
        m = fmaxf(fmaxf(redm[0], redm[1]), fmaxf(redm[2], redm[3]));
        float s = 0.0f, e[CNT];
#pragma unroll
        for (int i = 0; i < CNT; ++i) {
            e[i] = expf(vals[i] - m);
            s += e[i];
        }
        for (int off = 32; off; off >>= 1) s += __shfl_xor(s, off);
        __shared__ float reds[4];
        if ((tid & 63) == 0) reds[tid >> 6] = s;
        __syncthreads();
        s = reds[0] + reds[1] + reds[2] + reds[3];
        float inv = 1.0f / s;
#pragma unroll
        for (int i = 0; i < CNT; ++i)
            outT[(size_t)(i * 256 + tid) * NB + row] = e[i] * inv;
    }
}

extern "C" void kernel_launch(void* const* d_in, const int* in_sizes, int n_in,
                              void* d_out, int out_size, void* d_ws, size_t ws_size,
                              hipStream_t stream) {
    const float* x = (const float*)d_in[0];
    const float* W0 = (const float*)d_in[1];
    const float* thr0 = (const float*)d_in[2];
    const float* W1 = (const float*)d_in[3];
    const float* thr1 = (const float*)d_in[4];
    const float* W2 = (const float*)d_in[5];
    const float* thr2 = (const float*)d_in[6];
    const float* W3 = (const float*)d_in[7];
    const float* thr3 = (const float*)d_in[8];
    float* out = (float*)d_out;

    char* ws = (char*)d_ws;
    size_t off = 0;
    auto alloc = [&](size_t bytes) {
        void* p = ws + off;
        off += (bytes + 255) & ~(size_t)255;
        return p;
    };
    _Float16* Wh = (_Float16*)alloc((size_t)8192 * 8192 * 2);
    _Float16* Wl = (_Float16*)alloc((size_t)8192 * 8192 * 2);
    _Float16* Xh = (_Float16*)alloc((size_t)4096 * 8192 * 2);
    _Float16* Xl = (_Float16*)alloc((size_t)4096 * 8192 * 2);
    _Float16* Yh = (_Float16*)alloc((size_t)4096 * 8192 * 2);
    _Float16* Yl = (_Float16*)alloc((size_t)4096 * 8192 * 2);
    float* C32 = (float*)alloc((size_t)4096 * 8192 * 4);

    // x [4096 f][4096 b] -> Xt h/l [b][f]
    tsplit_kernel<<<dim3(64, 64), 256, 0, stream>>>(x, Xh, Xl);

    // layer 0: K=4096, M=8192, relu, k=409
    splitw_kernel<<<4096, 256, 0, stream>>>(W0, Wh, Wl, (long)8192 * 4096 / 4);
    gemm3_kernel<<<dim3(8192 / 128, NB / 128), 256, 0, stream>>>(Xh, Xl, Wh, Wl, C32, 4096, 8192, 1);
    kwta_kernel<32, false><<<NB, 256, 0, stream>>>(C32, thr0, Yh, Yl, nullptr, 8192, 409);

    // layer 1: K=8192, M=8192, relu, k=409
    splitw_kernel<<<4096, 256, 0, stream>>>(W1, Wh, Wl, (long)8192 * 8192 / 4);
    gemm3_kernel<<<dim3(8192 / 128, NB / 128), 256, 0, stream>>>(Yh, Yl, Wh, Wl, C32, 8192, 8192, 1);
    kwta_kernel<32, false><<<NB, 256, 0, stream>>>(C32, thr1, Xh, Xl, nullptr, 8192, 409);

    // layer 2: K=8192, M=4096, relu, k=204
    splitw_kernel<<<4096, 256, 0, stream>>>(W2, Wh, Wl, (long)4096 * 8192 / 4);
    gemm3_kernel<<<dim3(4096 / 128, NB / 128), 256, 0, stream>>>(Xh, Xl, Wh, Wl, C32, 8192, 4096, 1);
    kwta_kernel<16, false><<<NB, 256, 0, stream>>>(C32, thr2, Yh, Yl, nullptr, 4096, 204);

    // layer 3: K=4096, M=1024, no relu, k=51, then softmax -> out [1024][4096]
    splitw_kernel<<<4096, 256, 0, stream>>>(W3, Wh, Wl, (long)1024 * 4096 / 4);
    gemm3_kernel<<<dim3(1024 / 128, NB / 128), 256, 0, stream>>>(Yh, Yl, Wh, Wl, C32, 4096, 1024, 0);
    kwta_kernel<4, true><<<NB, 256, 0, stream>>>(C32, thr3, nullptr, nullptr, out, 1024, 51);
}